// Round 12
// baseline (312.699 us; speedup 1.0000x reference)
//
#include <hip/hip_runtime.h>

#define S_LEN 2048
#define H_DIM 2048
#define NH 32
#define NKV 8
#define HD 64
#define RLEN 1024
#define KVTOT 3072
#define SCALE 0.125f
// SCALE * log2(e): fold into Q during RoPE so QK^T lands in log2 domain
#define QS 0.18033688011112042f
// 8 * log2(e): fixed softmax max in log2 domain
#define FIX8 11.541560327111707f

typedef unsigned short ushort_t;
using short8 = __attribute__((ext_vector_type(8))) short;
using f32x4 = __attribute__((ext_vector_type(4))) float;

__device__ __forceinline__ float b2f(unsigned short u) {
    union { unsigned int i; float f; } v;
    v.i = ((unsigned int)u) << 16;
    return v.f;
}
__device__ __forceinline__ unsigned short f2b(float f) {
    union { float f; unsigned int i; } v;
    v.f = f;
    unsigned int x = v.i;
    return (unsigned short)((x + 0x7fffu + ((x >> 16) & 1u)) >> 16);
}

// async global->LDS, 16B per lane. LDS dest is WAVE-UNIFORM base; HW adds lane*16B.
__device__ __forceinline__ void gload16(const ushort_t* g, ushort_t* l) {
    __builtin_amdgcn_global_load_lds(
        (const __attribute__((address_space(1))) unsigned int*)g,
        (__attribute__((address_space(3))) unsigned int*)l, 16, 0, 0);
}

// ---- wave-uniform dtype self-detection (same rule as the old detect9) ----
__device__ __forceinline__ int is_f32(const void* p) {
    const unsigned int* w = (const unsigned int*)p;
    const int lane = threadIdx.x & 63;
    int cnt = 0;
#pragma unroll
    for (int j = 0; j < 4; ++j) {
        unsigned int lo = w[lane + j * 64] & 0xFFFFu;
        unsigned int e = (lo >> 7) & 0xFFu;
        cnt += (lo != 0u && (e < 90u || e > 140u)) ? 1 : 0;
    }
    unsigned long long b = __ballot(cnt >= 2);
    return __popcll(b) > 16;
}

// Q layout: [2048 rows][2048 cols], 32 head-blocks XOR-permuted per row:
// block cb of row si lives at cb ^ (si & 31). Bijective; kills the 4KB
// power-of-2 read aliasing (R8/R10 bisect) with a compact write.
__device__ __forceinline__ int qswz(int row, int cb) { return cb ^ (row & 31); }

// ---- prep_all: weight transposes + retrieval K/V + hs->bf16 (into d_out scratch) ----
__global__ __launch_bounds__(256) void prep_all(
    const void* __restrict__ rk, const void* __restrict__ rv,
    const void* __restrict__ Wq, const void* __restrict__ Wk,
    const void* __restrict__ Wv, const void* __restrict__ Wo,
    ushort_t* __restrict__ WqkvT, ushort_t* __restrict__ WoT,
    ushort_t* __restrict__ ktall, ushort_t* __restrict__ vtall,
    const void* __restrict__ hs, ushort_t* __restrict__ hsb)
{
    __shared__ ushort_t S[64 * 72];
    const int id = blockIdx.x;
    if (id >= 2944) {
        const int F = is_f32(hs);
        int i = ((id - 2944) * 256 + threadIdx.x) * 8;
        ushort_t o[8];
        if (F) {
            const float* p = (const float*)hs + i;
            float4 f0 = ((const float4*)p)[0];
            float4 f1 = ((const float4*)p)[1];
            o[0] = f2b(f0.x); o[1] = f2b(f0.y); o[2] = f2b(f0.z); o[3] = f2b(f0.w);
            o[4] = f2b(f1.x); o[5] = f2b(f1.y); o[6] = f2b(f1.z); o[7] = f2b(f1.w);
            *(uint4*)(hsb + i) = *(const uint4*)o;
        } else {
            *(uint4*)(hsb + i) = *(const uint4*)((const ushort_t*)hs + i);
        }
        return;
    }
    if (id < 2560) {
        int z, t;
        if (id < 1024)      { z = 0; t = id; }
        else if (id < 1280) { z = 1; t = id - 1024; }
        else if (id < 1536) { z = 2; t = id - 1280; }
        else                { z = 3; t = id - 1536; }
        const void* src = (z == 0) ? Wq : (z == 1) ? Wk : (z == 2) ? Wv : Wo;
        const int F = is_f32(src);
        const int C = (z == 1 || z == 2) ? 512 : 2048;
        const int nx = (z == 1 || z == 2) ? 8 : 32;
        const int x = t % nx, y = t / nx;
        ushort_t* dst = (z == 3) ? WoT : WqkvT;
        const int rofs = (z == 1) ? 2048 : (z == 2) ? 2560 : 0;

        const int r0 = y * 64, c0 = x * 64;
        const int lr = threadIdx.x >> 2, lc = (threadIdx.x & 3) * 16;
        ushort_t tt[16];
        if (F) {
            const float* p = (const float*)src + (size_t)(r0 + lr) * C + c0 + lc;
#pragma unroll
            for (int j = 0; j < 16; j += 4) {
                float4 f = *(const float4*)(p + j);
                tt[j] = f2b(f.x); tt[j + 1] = f2b(f.y); tt[j + 2] = f2b(f.z); tt[j + 3] = f2b(f.w);
            }
        } else {
            const ushort_t* p = (const ushort_t*)src + (size_t)(r0 + lr) * C + c0 + lc;
            *(uint4*)tt = ((const uint4*)p)[0];
            *(uint4*)(tt + 8) = ((const uint4*)p)[1];
        }
        *(uint4*)&S[lr * 72 + lc] = *(const uint4*)tt;
        *(uint4*)&S[lr * 72 + lc + 8] = *(const uint4*)(tt + 8);
        __syncthreads();
        const int wc = threadIdx.x >> 2, wr = (threadIdx.x & 3) * 16;
        ushort_t o[16];
#pragma unroll
        for (int j = 0; j < 16; ++j) o[j] = S[(wr + j) * 72 + wc];
        ushort_t* q = dst + (size_t)(rofs + c0 + wc) * 2048 + r0 + wr;
        *(uint4*)q = *(const uint4*)o;
        *(uint4*)(q + 8) = *(const uint4*)(o + 8);
    } else if (id < 2816) {
        // retrieval-K: rk[kvh][p][d] -> ktall rows 0..1023 (no RoPE, per reference)
        const int kF = is_f32(rk);
        const int e = ((id - 2560) * 256 + threadIdx.x) * 8;   // < 524288
        const int kvh = e >> 16;
        const int rem = e & 65535;
        ushort_t* dst = ktall + (size_t)kvh * (KVTOT * 64) + rem;
        if (kF) {
            const float* p = (const float*)rk + e;
            float4 f0 = ((const float4*)p)[0];
            float4 f1 = ((const float4*)p)[1];
            ushort_t o[8];
            o[0] = f2b(f0.x); o[1] = f2b(f0.y); o[2] = f2b(f0.z); o[3] = f2b(f0.w);
            o[4] = f2b(f1.x); o[5] = f2b(f1.y); o[6] = f2b(f1.z); o[7] = f2b(f1.w);
            *(uint4*)dst = *(const uint4*)o;
        } else {
            *(uint4*)dst = *(const uint4*)((const ushort_t*)rk + e);
        }
    } else {
        // retrieval-V transpose into vtall blks 0..31
        const int idv = id - 2816;
        const int t = idv & 15;
        const int kvh = idv >> 4;
        const int vF = is_f32(rv);
        const int lr = threadIdx.x >> 2, lc = (threadIdx.x & 3) * 16;
        ushort_t tt[16];
        size_t base = ((size_t)kvh * RLEN + t * 64 + lr) * HD + lc;
        if (vF) {
            const float* p = (const float*)rv + base;
#pragma unroll
            for (int j = 0; j < 16; j += 4) {
                float4 f = *(const float4*)(p + j);
                tt[j] = f2b(f.x); tt[j + 1] = f2b(f.y); tt[j + 2] = f2b(f.z); tt[j + 3] = f2b(f.w);
            }
        } else {
            const ushort_t* p = (const ushort_t*)rv + base;
            *(uint4*)tt = ((const uint4*)p)[0];
            *(uint4*)(tt + 8) = ((const uint4*)p)[1];
        }
        *(uint4*)&S[lr * 72 + lc] = *(const uint4*)tt;
        *(uint4*)&S[lr * 72 + lc + 8] = *(const uint4*)(tt + 8);
        __syncthreads();
        const int wc = threadIdx.x >> 2, wr = (threadIdx.x & 3) * 16;
        ushort_t o[16];
#pragma unroll
        for (int j = 0; j < 16; ++j) o[j] = S[(wr + j) * 72 + wc];
        const int blk = t * 2 + (wr >> 5);
        ushort_t* q = vtall + (((size_t)(kvh * 96 + blk) * 64 + wc) * 32) + (wr & 31);
        *(uint4*)q = *(const uint4*)o;
        *(uint4*)(q + 8) = *(const uint4*)(o + 8);
    }
}

// ---- gemm_qkv: all-bf16 gload_lds staging + fused epilogue ----
__global__ __launch_bounds__(256, 4) void gemm_qkv(
    const ushort_t* __restrict__ A, const ushort_t* __restrict__ Bt,
    ushort_t* __restrict__ qkvp, ushort_t* __restrict__ ktall,
    ushort_t* __restrict__ vtall,
    const void* __restrict__ cosv, const void* __restrict__ sinv)
{
    const int K = 2048;
    __shared__ __align__(16) ushort_t As[2][64 * 32];
    __shared__ __align__(16) ushort_t Bs[2][128 * 32];
    const int tid = threadIdx.x;
    const int wave = tid >> 6, lane = tid & 63;
    const int lq = lane & 15, quad = lane >> 4;
    const int m0 = blockIdx.y * 64, n0 = blockIdx.x * 128;
    const int wm = (wave & 1) * 32, wn = (wave >> 1) * 64;
    const int nk = K >> 5;

    const int srow = wave * 16 + (lane >> 2);
    const int scol = ((lane & 3) ^ ((lane >> 3) & 3)) * 8;   // inverse-swizzled source
    const ushort_t* ga  = A  + (size_t)(m0 + srow) * K + scol;
    const ushort_t* gb0 = Bt + (size_t)(n0 + srow) * K + scol;
    const ushort_t* gb1 = Bt + (size_t)(n0 + 64 + srow) * K + scol;
    ushort_t* lA = &As[0][0] + wave * 16 * 32;   // wave-uniform LDS bases
    ushort_t* lB = &Bs[0][0] + wave * 16 * 32;
    const int rs = (lq >> 1) & 3;                // read-slot swizzle

    f32x4 acc[2][4];
#pragma unroll
    for (int i = 0; i < 2; ++i)
#pragma unroll
        for (int j = 0; j < 4; ++j) acc[i][j] = (f32x4){0.f, 0.f, 0.f, 0.f};

#define STAGE_G(buf, kt) do { \
        gload16(ga  + (size_t)(kt) * 32, lA + (buf) * (64 * 32)); \
        gload16(gb0 + (size_t)(kt) * 32, lB + (buf) * (128 * 32)); \
        gload16(gb1 + (size_t)(kt) * 32, lB + (buf) * (128 * 32) + 64 * 32); \
    } while (0)

    STAGE_G(0, 0);
    int cur = 0;
    for (int kt = 0; kt < nk; ++kt) {
        if (kt + 1 < nk) {
            STAGE_G(cur ^ 1, kt + 1);
            asm volatile("s_waitcnt vmcnt(3)" ::: "memory");
        } else {
            asm volatile("s_waitcnt vmcnt(0)" ::: "memory");
        }
        __builtin_amdgcn_s_barrier();
        __builtin_amdgcn_sched_barrier(0);
        short8 afr[2], bfr[4];
#pragma unroll
        for (int i = 0; i < 2; ++i)
            afr[i] = *(const short8*)&As[cur][(wm + i * 16 + lq) * 32 + (quad ^ rs) * 8];
#pragma unroll
        for (int j = 0; j < 4; ++j)
            bfr[j] = *(const short8*)&Bs[cur][(wn + j * 16 + lq) * 32 + (quad ^ rs) * 8];
#pragma unroll
        for (int i = 0; i < 2; ++i)
#pragma unroll
            for (int j = 0; j < 4; ++j)
                acc[i][j] = __builtin_amdgcn_mfma_f32_16x16x32_bf16(afr[i], bfr[j], acc[i][j], 0, 0, 0);
        __builtin_amdgcn_s_barrier();
        cur ^= 1;
    }
#undef STAGE_G

    if (n0 < 2048) {
        // Q tile -> qkvp [2048][2048], head-block XOR-swizzled per row
        const int cb = (n0 + wn) >> 6;
#pragma unroll
        for (int i = 0; i < 2; ++i)
#pragma unroll
            for (int r = 0; r < 4; ++r) {
                const int si = m0 + wm + i * 16 + quad * 4 + r;
                ushort_t* cp = qkvp + (size_t)si * 2048 + (qswz(si, cb) << 6) + lq;
#pragma unroll
                for (int j = 0; j < 4; ++j) cp[j * 16] = f2b(acc[i][j][r]);
            }
    } else if (n0 < 2560) {
        // K tile -> fused RoPE (f32) -> ktall rows RLEN+si
        const int cF = is_f32(cosv), sF = is_f32(sinv);
        const int kvh = (n0 - 2048 + wn) >> 6;
#pragma unroll
        for (int i = 0; i < 2; ++i)
#pragma unroll
            for (int r = 0; r < 4; ++r) {
                const int si = m0 + wm + i * 16 + quad * 4 + r;
                const int ci = si * HD + lq;
                float c0, c1, c2, c3, s0, s1, s2, s3;
                if (cF) {
                    const float* cp = (const float*)cosv + ci;
                    c0 = cp[0]; c1 = cp[16]; c2 = cp[32]; c3 = cp[48];
                } else {
                    const ushort_t* cp = (const ushort_t*)cosv + ci;
                    c0 = b2f(cp[0]); c1 = b2f(cp[16]); c2 = b2f(cp[32]); c3 = b2f(cp[48]);
                }
                if (sF) {
                    const float* sp = (const float*)sinv + ci;
                    s0 = sp[0]; s1 = sp[16]; s2 = sp[32]; s3 = sp[48];
                } else {
                    const ushort_t* sp = (const ushort_t*)sinv + ci;
                    s0 = b2f(sp[0]); s1 = b2f(sp[16]); s2 = b2f(sp[32]); s3 = b2f(sp[48]);
                }
                ushort_t* kp = ktall + ((size_t)kvh * KVTOT + RLEN + si) * HD + lq;
                kp[0]  = f2b(acc[i][0][r] * c0 - acc[i][2][r] * s0);
                kp[16] = f2b(acc[i][1][r] * c1 - acc[i][3][r] * s1);
                kp[32] = f2b(acc[i][2][r] * c2 + acc[i][0][r] * s2);
                kp[48] = f2b(acc[i][3][r] * c3 + acc[i][1][r] * s3);
            }
    } else {
        // V tile -> transposed into vtall blks 32.. ([d][32 kv-slots])
        const int kvh = (n0 - 2560 + wn) >> 6;
#pragma unroll
        for (int i = 0; i < 2; ++i) {
            const int si0 = m0 + wm + i * 16 + quad * 4;
            const int blk = 32 + (si0 >> 5);
            const int slot = si0 & 31;
#pragma unroll
            for (int j = 0; j < 4; ++j) {
                const int d = j * 16 + lq;
                ushort_t o[4];
#pragma unroll
                for (int r = 0; r < 4; ++r) o[r] = f2b(acc[i][j][r]);
                *(uint2*)(vtall + ((size_t)(kvh * 96 + blk) * 64 + d) * 32 + slot) = *(const uint2*)o;
            }
        }
    }
}

// ---- gemm_fin: pipelined 64x128, dual-dtype output (self-detects via hs) ----
__global__ __launch_bounds__(256, 4) void gemm_fin(
    const ushort_t* __restrict__ A, const ushort_t* __restrict__ Bt,
    void* __restrict__ Cv, int N, int K, const void* __restrict__ hs)
{
    const int oF = is_f32(hs);
    __shared__ __align__(16) ushort_t As[2][64 * 32];
    __shared__ __align__(16) ushort_t Bs[2][128 * 32];
    const int tid = threadIdx.x;
    const int wave = tid >> 6, lane = tid & 63;
    const int lq = lane & 15, quad = lane >> 4;
    const int m0 = blockIdx.y * 64, n0 = blockIdx.x * 128;
    const int wm = (wave & 1) * 32, wn = (wave >> 1) * 64;
    const int nk = K >> 5;

    const int srow = wave * 16 + (lane >> 2);
    const int scol = ((lane & 3) ^ ((lane >> 3) & 3)) * 8;
    const ushort_t* ga  = A  + (size_t)(m0 + srow) * K + scol;
    const ushort_t* gb0 = Bt + (size_t)(n0 + srow) * K + scol;
    const ushort_t* gb1 = Bt + (size_t)(n0 + 64 + srow) * K + scol;
    ushort_t* lA = &As[0][0] + wave * 16 * 32;
    ushort_t* lB = &Bs[0][0] + wave * 16 * 32;
    const int rs = (lq >> 1) & 3;

    f32x4 acc[2][4];
#pragma unroll
    for (int i = 0; i < 2; ++i)
#pragma unroll
        for (int j = 0; j < 4; ++j) acc[i][j] = (f32x4){0.f, 0.f, 0.f, 0.f};

#define STAGE_G(buf, kt) do { \
        gload16(ga  + (size_t)(kt) * 32, lA + (buf) * (64 * 32)); \
        gload16(gb0 + (size_t)(kt) * 32, lB + (buf) * (128 * 32)); \
        gload16(gb1 + (size_t)(kt) * 32, lB + (buf) * (128 * 32) + 64 * 32); \
    } while (0)

    STAGE_G(0, 0);
    int cur = 0;
    for (int kt = 0; kt < nk; ++kt) {
        if (kt + 1 < nk) {
            STAGE_G(cur ^ 1, kt + 1);
            asm volatile("s_waitcnt vmcnt(3)" ::: "memory");
        } else {
            asm volatile("s_waitcnt vmcnt(0)" ::: "memory");
        }
        __builtin_amdgcn_s_barrier();
        __builtin_amdgcn_sched_barrier(0);
        short8 afr[2], bfr[4];
#pragma unroll
        for (int i = 0; i < 2; ++i)
            afr[i] = *(const short8*)&As[cur][(wm + i * 16 + lq) * 32 + (quad ^ rs) * 8];
#pragma unroll
        for (int j = 0; j < 4; ++j)
            bfr[j] = *(const short8*)&Bs[cur][(wn + j * 16 + lq) * 32 + (quad ^ rs) * 8];
#pragma unroll
        for (int i = 0; i < 2; ++i)
#pragma unroll
            for (int j = 0; j < 4; ++j)
                acc[i][j] = __builtin_amdgcn_mfma_f32_16x16x32_bf16(afr[i], bfr[j], acc[i][j], 0, 0, 0);
        __builtin_amdgcn_s_barrier();
        cur ^= 1;
    }

#pragma unroll
    for (int i = 0; i < 2; ++i)
#pragma unroll
        for (int r = 0; r < 4; ++r) {
            size_t off = (size_t)(m0 + wm + i * 16 + quad * 4 + r) * N + n0 + wn + lq;
            if (oF) {
                float* cp = (float*)Cv + off;
#pragma unroll
                for (int j = 0; j < 4; ++j) cp[j * 16] = acc[i][j][r];
            } else {
                ushort_t* cp = (ushort_t*)Cv + off;
#pragma unroll
                for (int j = 0; j < 4; ++j) cp[j * 16] = f2b(acc[i][j][r]);
            }
        }
#undef STAGE_G
}

// ---- Flash attention (R11 structure): swapped QK^T + packed P-store,
// Q block-swizzle read, -FIX8 C-init ----
__global__ __launch_bounds__(256) void fattn(
    const ushort_t* __restrict__ qkvp, const ushort_t* __restrict__ ktall,
    const ushort_t* __restrict__ vtall, ushort_t* __restrict__ attno,
    const void* __restrict__ cosv, const void* __restrict__ sinv)
{
    const int cF = is_f32(cosv), sF = is_f32(sinv);
    const int h = blockIdx.x;
    const int yy = blockIdx.y;
    const int st = yy >> 3, r8 = yy & 7;
    const int qb = (st == 0) ? (31 - r8) : (st == 1) ? (16 + r8)
                 : (st == 2) ? (15 - r8) : r8;
    const int kvh = h >> 2;
    const int tid = threadIdx.x;
    const int wave = tid >> 6;
    const int lane = tid & 63;
    const int lq = lane & 15;
    const int quad = lane >> 4;
    const int rb64 = ((qb < 17 ? qb : 16) - 1) * 64;
    const int qrow = qb * 64 + wave * 16 + lq;

    __shared__ __align__(16) ushort_t Ks[128 * 72];
    __shared__ __align__(16) ushort_t Ps[4 * 16 * 136];
    ushort_t* pw = &Ps[wave * 16 * 136];

    short8 qfrag[2];
    {
        const int row_g = qb * 64 + wave * 16 + lq;
        const ushort_t* qrp = qkvp + (size_t)row_g * 2048 + (qswz(row_g, h) << 6);
        short8 t0 = *(const short8*)(qrp + quad * 8);
        short8 t1 = *(const short8*)(qrp + 32 + quad * 8);
        const int ci = row_g * HD + quad * 8;
        float c0[8], c1[8], s0[8], s1[8];
        if (cF) {
            const float* cp = (const float*)cosv + ci;
#pragma unroll
            for (int j = 0; j < 8; ++j) { c0[j] = cp[j]; c1[j] = cp[j + 32]; }
        } else {
            const ushort_t* cp = (const ushort_t*)cosv + ci;
#pragma unroll
            for (int j = 0; j < 8; ++j) { c0[j] = b2f(cp[j]); c1[j] = b2f(cp[j + 32]); }
        }
        if (sF) {
            const float* sp = (const float*)sinv + ci;
#pragma unroll
            for (int j = 0; j < 8; ++j) { s0[j] = sp[j]; s1[j] = sp[j + 32]; }
        } else {
            const ushort_t* sp = (const ushort_t*)sinv + ci;
#pragma unroll
            for (int j = 0; j < 8; ++j) { s0[j] = b2f(sp[j]); s1[j] = b2f(sp[j + 32]); }
        }
#pragma unroll
        for (int j = 0; j < 8; ++j) {
            float a = b2f((unsigned short)t0[j]), b = b2f((unsigned short)t1[j]);
            qfrag[0][j] = (short)f2b((a * c0[j] - b * s0[j]) * QS);
            qfrag[1][j] = (short)f2b((b * c1[j] + a * s1[j]) * QS);
        }
    }

    f32x4 oacc[4];
#pragma unroll
    for (int nt = 0; nt < 4; ++nt) oacc[nt] = (f32x4){0.f, 0.f, 0.f, 0.f};
    float lsum = 0.f;

    const int Lq = (qb > 0) ? qb * 64 + 128 : 64;
    const int nch = (Lq + 127) >> 7;
    const ushort_t* kbase = ktall + (size_t)kvh * KVTOT * HD;
    const ushort_t* vbase = vtall + (size_t)kvh * 96 * 2048;

    for (int c = 0; c < nch; ++c) {
        uint4 kreg0, kreg1, kreg2, kreg3;
        const int krow = tid >> 1;
        const int kd0 = (tid & 1) * 32;
        {
            int p = c * 128 + krow;
            uint4 z = {0, 0, 0, 0};
            kreg0 = z; kreg1 = z; kreg2 = z; kreg3 = z;
            if (p < Lq) {
                int pk = (qb > 0) ? ((p < 64) ? rb64 + p : 960 + p) : RLEN + p;
                const uint4* s = (const uint4*)(kbase + (size_t)pk * HD + kd0);
                kreg0 = s[0]; kreg1 = s[1]; kreg2 = s[2]; kreg3 = s[3];
            }
        }
        int vblk[4];
#pragma unroll
        for (int kc = 0; kc < 4; ++kc) {
            int p = c * 128 + kc * 32;
            int pk = (qb > 0) ? ((p < 64) ? rb64 + p : 960 + p) : RLEN + p;
            if (pk > KVTOT - 1) pk = KVTOT - 1;
            vblk[kc] = pk >> 5;
        }
        short8 vfA[4], vfB[4];
#pragma unroll
        for (int ntd = 0; ntd < 4; ++ntd)
            vfA[ntd] = *(const short8*)(vbase + ((size_t)vblk[0] * 64 + ntd * 16 + lq) * 32 + quad * 8);
#pragma unroll
        for (int ntd = 0; ntd < 4; ++ntd)
            vfB[ntd] = *(const short8*)(vbase + ((size_t)vblk[1] * 64 + ntd * 16 + lq) * 32 + quad * 8);

        {
            uint4* dk = (uint4*)&Ks[krow * 72 + kd0];
            dk[0] = kreg0; dk[1] = kreg1; dk[2] = kreg2; dk[3] = kreg3;
        }
        __syncthreads();

        const bool lastc = (c == nch - 1) || (qb == 0);
#pragma unroll
        for (int nt = 0; nt < 8; ++nt) {
            f32x4 a = (f32x4){-FIX8, -FIX8, -FIX8, -FIX8};   // C-init folds the subtract
            a = __builtin_amdgcn_mfma_f32_16x16x32_bf16(
                *(const short8*)&Ks[(nt * 16 + lq) * 72 + quad * 8], qfrag[0], a, 0, 0, 0);
            a = __builtin_amdgcn_mfma_f32_16x16x32_bf16(
                *(const short8*)&Ks[(nt * 16 + lq) * 72 + 32 + quad * 8], qfrag[1], a, 0, 0, 0);
            float pex[4];
#pragma unroll
            for (int rr = 0; rr < 4; ++rr) {
                const int p = c * 128 + nt * 16 + quad * 4 + rr;
                float pexp = exp2f(a[rr]);
                if (lastc) {
                    bool valid;
                    if (qb > 0) valid = (p < 64) || ((p - 64) >= 1 && (p - 64) <= qrow);
                    else        valid = (p >= 1 && p <= qrow);
                    if (!valid) pexp = 0.f;
                } else if (c == 0) {
                    if (p == 64) pexp = 0.f;
                }
                lsum += pexp;
                pex[rr] = pexp;
            }
            unsigned int w0, w1;
            asm("v_cvt_pk_bf16_f32 %0, %1, %2" : "=v"(w0) : "v"(pex[0]), "v"(pex[1]));
            asm("v_cvt_pk_bf16_f32 %0, %1, %2" : "=v"(w1) : "v"(pex[2]), "v"(pex[3]));
            *(uint2*)&pw[lq * 136 + nt * 16 + quad * 4] = make_uint2(w0, w1);
        }

#pragma unroll
        for (int kc = 0; kc < 4; ++kc) {
            short8 pa = *(const short8*)&pw[lq * 136 + kc * 32 + quad * 8];
            short8 vf0, vf1, vf2, vf3;
            if (kc == 0)      { vf0 = vfA[0]; vf1 = vfA[1]; vf2 = vfA[2]; vf3 = vfA[3]; }
            else if (kc == 1) { vf0 = vfB[0]; vf1 = vfB[1]; vf2 = vfB[2]; vf3 = vfB[3]; }
            else {
                const int b = vblk[kc];
                vf0 = *(const short8*)(vbase + ((size_t)b * 64 + 0 * 16 + lq) * 32 + quad * 8);
                vf1 = *(const short8*)(vbase + ((size_t)b * 64 + 1 * 16 + lq) * 32 + quad * 8);
                vf2 = *(const short8*)(vbase + ((size_t)b * 64 + 2 * 16 + lq) * 32 + quad * 8);
                vf3 = *(const short8*)(vbase + ((size_t)b * 64 + 3 * 16 + lq) * 32 + quad * 8);
            }
            oacc[0] = __builtin_amdgcn_mfma_f32_16x16x32_bf16(pa, vf0, oacc[0], 0, 0, 0);
            oacc[1] = __builtin_amdgcn_mfma_f32_16x16x32_bf16(pa, vf1, oacc[1], 0, 0, 0);
            oacc[2] = __builtin_amdgcn_mfma_f32_16x16x32_bf16(pa, vf2, oacc[2], 0, 0, 0);
            oacc[3] = __builtin_amdgcn_mfma_f32_16x16x32_bf16(pa, vf3, oacc[3], 0, 0, 0);
        }
        __syncthreads();
    }

    float tot = lsum;
    tot += __shfl_xor(tot, 16, 64);
    tot += __shfl_xor(tot, 32, 64);
#pragma unroll
    for (int rr = 0; rr < 4; ++rr) {
        const int qg = qb * 64 + wave * 16 + quad * 4 + rr;
        const float tr = __shfl(tot, quad * 4 + rr, 64);
        const float inv = (qg == 0) ? 0.f : 1.f / tr;
        ushort_t* orow = attno + (size_t)qg * 2048 + h * HD;
#pragma unroll
        for (int nt = 0; nt < 4; ++nt)
            orow[nt * 16 + lq] = f2b(oacc[nt][rr] * inv);
    }
}

extern "C" void kernel_launch(void* const* d_in, const int* in_sizes, int n_in,
                              void* d_out, int out_size, void* d_ws, size_t ws_size,
                              hipStream_t stream) {
    const void* hs   = d_in[0];
    const void* cosv = d_in[1];
    const void* sinv = d_in[2];
    const void* rk   = d_in[3];
    const void* rv   = d_in[4];
    const void* Wq   = d_in[5];
    const void* Wk   = d_in[6];
    const void* Wv   = d_in[7];
    const void* Wo   = d_in[8];

    char* ws = (char*)d_ws;
    ushort_t* ktall = (ushort_t*)ws;                       // 0..3MB
    ushort_t* vtall = (ushort_t*)(ws + (3u  << 20));       // 3..6MB
    ushort_t* WqkvT = (ushort_t*)(ws + (6u  << 20));       // 6..18MB [3072][2048]
    ushort_t* WoT   = (ushort_t*)(ws + (18u << 20));       // 18..26MB
    ushort_t* qkvp  = (ushort_t*)(ws + (26u << 20));       // 26..34MB (Q, swizzled blocks)
    ushort_t* attno = WqkvT;                               // alias; WqkvT dead after gemm_qkv
    ushort_t* hsb   = (ushort_t*)d_out;                    // scratch until gemm_fin

    // MEASUREMENT PROBE (R12): prep_all and gemm_qkv launched TWICE (both
    // idempotent: they read only buffers they do not write). Delta vs R11's
    // 251.9us = T_prep + T_qkv (warm) + ~2 boundaries. Output bit-identical.
    prep_all<<<4992, 256, 0, stream>>>(rk, rv, Wq, Wk, Wv, Wo, WqkvT, WoT, ktall, vtall, hs, hsb);
    prep_all<<<4992, 256, 0, stream>>>(rk, rv, Wq, Wk, Wv, Wo, WqkvT, WoT, ktall, vtall, hs, hsb);

    gemm_qkv<<<dim3(24, 32), 256, 0, stream>>>(hsb, WqkvT, qkvp, ktall, vtall, cosv, sinv);
    gemm_qkv<<<dim3(24, 32), 256, 0, stream>>>(hsb, WqkvT, qkvp, ktall, vtall, cosv, sinv);

    fattn<<<dim3(NH, 32), 256, 0, stream>>>(qkvp, ktall, vtall, attno, cosv, sinv);

    gemm_fin<<<dim3(16, 32), 256, 0, stream>>>(attno, WoT, d_out, 2048, 2048, hs);
}

// Round 13
// 251.080 us; speedup vs baseline: 1.2454x; 1.2454x over previous
//
#include <hip/hip_runtime.h>

#define S_LEN 2048
#define H_DIM 2048
#define NH 32
#define NKV 8
#define HD 64
#define RLEN 1024
#define KVTOT 3072
#define SCALE 0.125f
// SCALE * log2(e): fold into Q during RoPE so QK^T lands in log2 domain
#define QS 0.18033688011112042f
// 8 * log2(e): fixed softmax max in log2 domain
#define FIX8 11.541560327111707f

typedef unsigned short ushort_t;
using short8 = __attribute__((ext_vector_type(8))) short;
using f32x4 = __attribute__((ext_vector_type(4))) float;

__device__ __forceinline__ float b2f(unsigned short u) {
    union { unsigned int i; float f; } v;
    v.i = ((unsigned int)u) << 16;
    return v.f;
}
__device__ __forceinline__ unsigned short f2b(float f) {
    union { float f; unsigned int i; } v;
    v.f = f;
    unsigned int x = v.i;
    return (unsigned short)((x + 0x7fffu + ((x >> 16) & 1u)) >> 16);
}

// async global->LDS, 16B per lane. LDS dest is WAVE-UNIFORM base; HW adds lane*16B.
__device__ __forceinline__ void gload16(const ushort_t* g, ushort_t* l) {
    __builtin_amdgcn_global_load_lds(
        (const __attribute__((address_space(1))) unsigned int*)g,
        (__attribute__((address_space(3))) unsigned int*)l, 16, 0, 0);
}

// ---- wave-uniform dtype self-detection (same rule as the old detect9) ----
__device__ __forceinline__ int is_f32(const void* p) {
    const unsigned int* w = (const unsigned int*)p;
    const int lane = threadIdx.x & 63;
    int cnt = 0;
#pragma unroll
    for (int j = 0; j < 4; ++j) {
        unsigned int lo = w[lane + j * 64] & 0xFFFFu;
        unsigned int e = (lo >> 7) & 0xFFu;
        cnt += (lo != 0u && (e < 90u || e > 140u)) ? 1 : 0;
    }
    unsigned long long b = __ballot(cnt >= 2);
    return __popcll(b) > 16;
}

// Q layout: [2048 rows][2048 cols], 32 head-blocks XOR-permuted per row:
// block cb of row si lives at cb ^ (si & 31). Bijective; kills the 4KB
// power-of-2 read aliasing (R8/R10 bisect) with a compact write.
__device__ __forceinline__ int qswz(int row, int cb) { return cb ^ (row & 31); }

// ---- prep_all: weight transposes + retrieval K/V + hs->bf16 (into d_out scratch) ----
__global__ __launch_bounds__(256) void prep_all(
    const void* __restrict__ rk, const void* __restrict__ rv,
    const void* __restrict__ Wq, const void* __restrict__ Wk,
    const void* __restrict__ Wv, const void* __restrict__ Wo,
    ushort_t* __restrict__ WqkvT, ushort_t* __restrict__ WoT,
    ushort_t* __restrict__ ktall, ushort_t* __restrict__ vtall,
    const void* __restrict__ hs, ushort_t* __restrict__ hsb)
{
    __shared__ ushort_t S[64 * 72];
    const int id = blockIdx.x;
    if (id >= 2944) {
        const int F = is_f32(hs);
        int i = ((id - 2944) * 256 + threadIdx.x) * 8;
        ushort_t o[8];
        if (F) {
            const float* p = (const float*)hs + i;
            float4 f0 = ((const float4*)p)[0];
            float4 f1 = ((const float4*)p)[1];
            o[0] = f2b(f0.x); o[1] = f2b(f0.y); o[2] = f2b(f0.z); o[3] = f2b(f0.w);
            o[4] = f2b(f1.x); o[5] = f2b(f1.y); o[6] = f2b(f1.z); o[7] = f2b(f1.w);
            *(uint4*)(hsb + i) = *(const uint4*)o;
        } else {
            *(uint4*)(hsb + i) = *(const uint4*)((const ushort_t*)hs + i);
        }
        return;
    }
    if (id < 2560) {
        int z, t;
        if (id < 1024)      { z = 0; t = id; }
        else if (id < 1280) { z = 1; t = id - 1024; }
        else if (id < 1536) { z = 2; t = id - 1280; }
        else                { z = 3; t = id - 1536; }
        const void* src = (z == 0) ? Wq : (z == 1) ? Wk : (z == 2) ? Wv : Wo;
        const int F = is_f32(src);
        const int C = (z == 1 || z == 2) ? 512 : 2048;
        const int nx = (z == 1 || z == 2) ? 8 : 32;
        const int x = t % nx, y = t / nx;
        ushort_t* dst = (z == 3) ? WoT : WqkvT;
        const int rofs = (z == 1) ? 2048 : (z == 2) ? 2560 : 0;

        const int r0 = y * 64, c0 = x * 64;
        const int lr = threadIdx.x >> 2, lc = (threadIdx.x & 3) * 16;
        ushort_t tt[16];
        if (F) {
            const float* p = (const float*)src + (size_t)(r0 + lr) * C + c0 + lc;
#pragma unroll
            for (int j = 0; j < 16; j += 4) {
                float4 f = *(const float4*)(p + j);
                tt[j] = f2b(f.x); tt[j + 1] = f2b(f.y); tt[j + 2] = f2b(f.z); tt[j + 3] = f2b(f.w);
            }
        } else {
            const ushort_t* p = (const ushort_t*)src + (size_t)(r0 + lr) * C + c0 + lc;
            *(uint4*)tt = ((const uint4*)p)[0];
            *(uint4*)(tt + 8) = ((const uint4*)p)[1];
        }
        *(uint4*)&S[lr * 72 + lc] = *(const uint4*)tt;
        *(uint4*)&S[lr * 72 + lc + 8] = *(const uint4*)(tt + 8);
        __syncthreads();
        const int wc = threadIdx.x >> 2, wr = (threadIdx.x & 3) * 16;
        ushort_t o[16];
#pragma unroll
        for (int j = 0; j < 16; ++j) o[j] = S[(wr + j) * 72 + wc];
        ushort_t* q = dst + (size_t)(rofs + c0 + wc) * 2048 + r0 + wr;
        *(uint4*)q = *(const uint4*)o;
        *(uint4*)(q + 8) = *(const uint4*)(o + 8);
    } else if (id < 2816) {
        // retrieval-K: rk[kvh][p][d] -> ktall rows 0..1023 (no RoPE, per reference)
        const int kF = is_f32(rk);
        const int e = ((id - 2560) * 256 + threadIdx.x) * 8;   // < 524288
        const int kvh = e >> 16;
        const int rem = e & 65535;
        ushort_t* dst = ktall + (size_t)kvh * (KVTOT * 64) + rem;
        if (kF) {
            const float* p = (const float*)rk + e;
            float4 f0 = ((const float4*)p)[0];
            float4 f1 = ((const float4*)p)[1];
            ushort_t o[8];
            o[0] = f2b(f0.x); o[1] = f2b(f0.y); o[2] = f2b(f0.z); o[3] = f2b(f0.w);
            o[4] = f2b(f1.x); o[5] = f2b(f1.y); o[6] = f2b(f1.z); o[7] = f2b(f1.w);
            *(uint4*)dst = *(const uint4*)o;
        } else {
            *(uint4*)dst = *(const uint4*)((const ushort_t*)rk + e);
        }
    } else {
        // retrieval-V transpose into vtall blks 0..31
        const int idv = id - 2816;
        const int t = idv & 15;
        const int kvh = idv >> 4;
        const int vF = is_f32(rv);
        const int lr = threadIdx.x >> 2, lc = (threadIdx.x & 3) * 16;
        ushort_t tt[16];
        size_t base = ((size_t)kvh * RLEN + t * 64 + lr) * HD + lc;
        if (vF) {
            const float* p = (const float*)rv + base;
#pragma unroll
            for (int j = 0; j < 16; j += 4) {
                float4 f = *(const float4*)(p + j);
                tt[j] = f2b(f.x); tt[j + 1] = f2b(f.y); tt[j + 2] = f2b(f.z); tt[j + 3] = f2b(f.w);
            }
        } else {
            const ushort_t* p = (const ushort_t*)rv + base;
            *(uint4*)tt = ((const uint4*)p)[0];
            *(uint4*)(tt + 8) = ((const uint4*)p)[1];
        }
        *(uint4*)&S[lr * 72 + lc] = *(const uint4*)tt;
        *(uint4*)&S[lr * 72 + lc + 8] = *(const uint4*)(tt + 8);
        __syncthreads();
        const int wc = threadIdx.x >> 2, wr = (threadIdx.x & 3) * 16;
        ushort_t o[16];
#pragma unroll
        for (int j = 0; j < 16; ++j) o[j] = S[(wr + j) * 72 + wc];
        const int blk = t * 2 + (wr >> 5);
        ushort_t* q = vtall + (((size_t)(kvh * 96 + blk) * 64 + wc) * 32) + (wr & 31);
        *(uint4*)q = *(const uint4*)o;
        *(uint4*)(q + 8) = *(const uint4*)(o + 8);
    }
}

// ---- gemm_qkv: all-bf16 gload_lds staging + fused epilogue ----
__global__ __launch_bounds__(256, 4) void gemm_qkv(
    const ushort_t* __restrict__ A, const ushort_t* __restrict__ Bt,
    ushort_t* __restrict__ qkvp, ushort_t* __restrict__ ktall,
    ushort_t* __restrict__ vtall,
    const void* __restrict__ cosv, const void* __restrict__ sinv)
{
    const int K = 2048;
    __shared__ __align__(16) ushort_t As[2][64 * 32];
    __shared__ __align__(16) ushort_t Bs[2][128 * 32];
    const int tid = threadIdx.x;
    const int wave = tid >> 6, lane = tid & 63;
    const int lq = lane & 15, quad = lane >> 4;
    const int m0 = blockIdx.y * 64, n0 = blockIdx.x * 128;
    const int wm = (wave & 1) * 32, wn = (wave >> 1) * 64;
    const int nk = K >> 5;

    const int srow = wave * 16 + (lane >> 2);
    const int scol = ((lane & 3) ^ ((lane >> 3) & 3)) * 8;   // inverse-swizzled source
    const ushort_t* ga  = A  + (size_t)(m0 + srow) * K + scol;
    const ushort_t* gb0 = Bt + (size_t)(n0 + srow) * K + scol;
    const ushort_t* gb1 = Bt + (size_t)(n0 + 64 + srow) * K + scol;
    ushort_t* lA = &As[0][0] + wave * 16 * 32;   // wave-uniform LDS bases
    ushort_t* lB = &Bs[0][0] + wave * 16 * 32;
    const int rs = (lq >> 1) & 3;                // read-slot swizzle

    f32x4 acc[2][4];
#pragma unroll
    for (int i = 0; i < 2; ++i)
#pragma unroll
        for (int j = 0; j < 4; ++j) acc[i][j] = (f32x4){0.f, 0.f, 0.f, 0.f};

#define STAGE_G(buf, kt) do { \
        gload16(ga  + (size_t)(kt) * 32, lA + (buf) * (64 * 32)); \
        gload16(gb0 + (size_t)(kt) * 32, lB + (buf) * (128 * 32)); \
        gload16(gb1 + (size_t)(kt) * 32, lB + (buf) * (128 * 32) + 64 * 32); \
    } while (0)

    STAGE_G(0, 0);
    int cur = 0;
    for (int kt = 0; kt < nk; ++kt) {
        if (kt + 1 < nk) {
            STAGE_G(cur ^ 1, kt + 1);
            asm volatile("s_waitcnt vmcnt(3)" ::: "memory");
        } else {
            asm volatile("s_waitcnt vmcnt(0)" ::: "memory");
        }
        __builtin_amdgcn_s_barrier();
        __builtin_amdgcn_sched_barrier(0);
        short8 afr[2], bfr[4];
#pragma unroll
        for (int i = 0; i < 2; ++i)
            afr[i] = *(const short8*)&As[cur][(wm + i * 16 + lq) * 32 + (quad ^ rs) * 8];
#pragma unroll
        for (int j = 0; j < 4; ++j)
            bfr[j] = *(const short8*)&Bs[cur][(wn + j * 16 + lq) * 32 + (quad ^ rs) * 8];
#pragma unroll
        for (int i = 0; i < 2; ++i)
#pragma unroll
            for (int j = 0; j < 4; ++j)
                acc[i][j] = __builtin_amdgcn_mfma_f32_16x16x32_bf16(afr[i], bfr[j], acc[i][j], 0, 0, 0);
        __builtin_amdgcn_s_barrier();
        cur ^= 1;
    }
#undef STAGE_G

    if (n0 < 2048) {
        // Q tile -> qkvp [2048][2048], head-block XOR-swizzled per row
        const int cb = (n0 + wn) >> 6;
#pragma unroll
        for (int i = 0; i < 2; ++i)
#pragma unroll
            for (int r = 0; r < 4; ++r) {
                const int si = m0 + wm + i * 16 + quad * 4 + r;
                ushort_t* cp = qkvp + (size_t)si * 2048 + (qswz(si, cb) << 6) + lq;
#pragma unroll
                for (int j = 0; j < 4; ++j) cp[j * 16] = f2b(acc[i][j][r]);
            }
    } else if (n0 < 2560) {
        // K tile -> fused RoPE (f32) -> ktall rows RLEN+si
        const int cF = is_f32(cosv), sF = is_f32(sinv);
        const int kvh = (n0 - 2048 + wn) >> 6;
#pragma unroll
        for (int i = 0; i < 2; ++i)
#pragma unroll
            for (int r = 0; r < 4; ++r) {
                const int si = m0 + wm + i * 16 + quad * 4 + r;
                const int ci = si * HD + lq;
                float c0, c1, c2, c3, s0, s1, s2, s3;
                if (cF) {
                    const float* cp = (const float*)cosv + ci;
                    c0 = cp[0]; c1 = cp[16]; c2 = cp[32]; c3 = cp[48];
                } else {
                    const ushort_t* cp = (const ushort_t*)cosv + ci;
                    c0 = b2f(cp[0]); c1 = b2f(cp[16]); c2 = b2f(cp[32]); c3 = b2f(cp[48]);
                }
                if (sF) {
                    const float* sp = (const float*)sinv + ci;
                    s0 = sp[0]; s1 = sp[16]; s2 = sp[32]; s3 = sp[48];
                } else {
                    const ushort_t* sp = (const ushort_t*)sinv + ci;
                    s0 = b2f(sp[0]); s1 = b2f(sp[16]); s2 = b2f(sp[32]); s3 = b2f(sp[48]);
                }
                ushort_t* kp = ktall + ((size_t)kvh * KVTOT + RLEN + si) * HD + lq;
                kp[0]  = f2b(acc[i][0][r] * c0 - acc[i][2][r] * s0);
                kp[16] = f2b(acc[i][1][r] * c1 - acc[i][3][r] * s1);
                kp[32] = f2b(acc[i][2][r] * c2 + acc[i][0][r] * s2);
                kp[48] = f2b(acc[i][3][r] * c3 + acc[i][1][r] * s3);
            }
    } else {
        // V tile -> transposed into vtall blks 32.. ([d][32 kv-slots])
        const int kvh = (n0 - 2560 + wn) >> 6;
#pragma unroll
        for (int i = 0; i < 2; ++i) {
            const int si0 = m0 + wm + i * 16 + quad * 4;
            const int blk = 32 + (si0 >> 5);
            const int slot = si0 & 31;
#pragma unroll
            for (int j = 0; j < 4; ++j) {
                const int d = j * 16 + lq;
                ushort_t o[4];
#pragma unroll
                for (int r = 0; r < 4; ++r) o[r] = f2b(acc[i][j][r]);
                *(uint2*)(vtall + ((size_t)(kvh * 96 + blk) * 64 + d) * 32 + slot) = *(const uint2*)o;
            }
        }
    }
}

// ---- gemm_fin: pipelined 64x128, dual-dtype output (self-detects via hs) ----
__global__ __launch_bounds__(256, 4) void gemm_fin(
    const ushort_t* __restrict__ A, const ushort_t* __restrict__ Bt,
    void* __restrict__ Cv, int N, int K, const void* __restrict__ hs)
{
    const int oF = is_f32(hs);
    __shared__ __align__(16) ushort_t As[2][64 * 32];
    __shared__ __align__(16) ushort_t Bs[2][128 * 32];
    const int tid = threadIdx.x;
    const int wave = tid >> 6, lane = tid & 63;
    const int lq = lane & 15, quad = lane >> 4;
    const int m0 = blockIdx.y * 64, n0 = blockIdx.x * 128;
    const int wm = (wave & 1) * 32, wn = (wave >> 1) * 64;
    const int nk = K >> 5;

    const int srow = wave * 16 + (lane >> 2);
    const int scol = ((lane & 3) ^ ((lane >> 3) & 3)) * 8;
    const ushort_t* ga  = A  + (size_t)(m0 + srow) * K + scol;
    const ushort_t* gb0 = Bt + (size_t)(n0 + srow) * K + scol;
    const ushort_t* gb1 = Bt + (size_t)(n0 + 64 + srow) * K + scol;
    ushort_t* lA = &As[0][0] + wave * 16 * 32;
    ushort_t* lB = &Bs[0][0] + wave * 16 * 32;
    const int rs = (lq >> 1) & 3;

    f32x4 acc[2][4];
#pragma unroll
    for (int i = 0; i < 2; ++i)
#pragma unroll
        for (int j = 0; j < 4; ++j) acc[i][j] = (f32x4){0.f, 0.f, 0.f, 0.f};

#define STAGE_G(buf, kt) do { \
        gload16(ga  + (size_t)(kt) * 32, lA + (buf) * (64 * 32)); \
        gload16(gb0 + (size_t)(kt) * 32, lB + (buf) * (128 * 32)); \
        gload16(gb1 + (size_t)(kt) * 32, lB + (buf) * (128 * 32) + 64 * 32); \
    } while (0)

    STAGE_G(0, 0);
    int cur = 0;
    for (int kt = 0; kt < nk; ++kt) {
        if (kt + 1 < nk) {
            STAGE_G(cur ^ 1, kt + 1);
            asm volatile("s_waitcnt vmcnt(3)" ::: "memory");
        } else {
            asm volatile("s_waitcnt vmcnt(0)" ::: "memory");
        }
        __builtin_amdgcn_s_barrier();
        __builtin_amdgcn_sched_barrier(0);
        short8 afr[2], bfr[4];
#pragma unroll
        for (int i = 0; i < 2; ++i)
            afr[i] = *(const short8*)&As[cur][(wm + i * 16 + lq) * 32 + (quad ^ rs) * 8];
#pragma unroll
        for (int j = 0; j < 4; ++j)
            bfr[j] = *(const short8*)&Bs[cur][(wn + j * 16 + lq) * 32 + (quad ^ rs) * 8];
#pragma unroll
        for (int i = 0; i < 2; ++i)
#pragma unroll
            for (int j = 0; j < 4; ++j)
                acc[i][j] = __builtin_amdgcn_mfma_f32_16x16x32_bf16(afr[i], bfr[j], acc[i][j], 0, 0, 0);
        __builtin_amdgcn_s_barrier();
        cur ^= 1;
    }

#pragma unroll
    for (int i = 0; i < 2; ++i)
#pragma unroll
        for (int r = 0; r < 4; ++r) {
            size_t off = (size_t)(m0 + wm + i * 16 + quad * 4 + r) * N + n0 + wn + lq;
            if (oF) {
                float* cp = (float*)Cv + off;
#pragma unroll
                for (int j = 0; j < 4; ++j) cp[j * 16] = acc[i][j][r];
            } else {
                ushort_t* cp = (ushort_t*)Cv + off;
#pragma unroll
                for (int j = 0; j < 4; ++j) cp[j * 16] = f2b(acc[i][j][r]);
            }
        }
#undef STAGE_G
}

// ---- Flash attention v8: chunk-level K double-buffer (T14 async split) ----
// Old order exposed the K-load->LDS-write vmcnt wait at every chunk top.
// New order: write K(c)->LDS / barrier / ISSUE K(c+1)+V loads (land under
// QK^T+softmax) / QK^T+softmax / barrier (gates Ks reads only; next-chunk
// ds_write overlaps other waves' PV) / PV. Same 2 barriers, same registers
// (kreg reused), latency moved from exposed to covered.
__global__ __launch_bounds__(256) void fattn(
    const ushort_t* __restrict__ qkvp, const ushort_t* __restrict__ ktall,
    const ushort_t* __restrict__ vtall, ushort_t* __restrict__ attno,
    const void* __restrict__ cosv, const void* __restrict__ sinv)
{
    const int cF = is_f32(cosv), sF = is_f32(sinv);
    const int h = blockIdx.x;
    const int yy = blockIdx.y;
    const int st = yy >> 3, r8 = yy & 7;
    const int qb = (st == 0) ? (31 - r8) : (st == 1) ? (16 + r8)
                 : (st == 2) ? (15 - r8) : r8;
    const int kvh = h >> 2;
    const int tid = threadIdx.x;
    const int wave = tid >> 6;
    const int lane = tid & 63;
    const int lq = lane & 15;
    const int quad = lane >> 4;
    const int rb64 = ((qb < 17 ? qb : 16) - 1) * 64;
    const int qrow = qb * 64 + wave * 16 + lq;

    __shared__ __align__(16) ushort_t Ks[128 * 72];
    __shared__ __align__(16) ushort_t Ps[4 * 16 * 136];
    ushort_t* pw = &Ps[wave * 16 * 136];

    short8 qfrag[2];
    {
        const int row_g = qb * 64 + wave * 16 + lq;
        const ushort_t* qrp = qkvp + (size_t)row_g * 2048 + (qswz(row_g, h) << 6);
        short8 t0 = *(const short8*)(qrp + quad * 8);
        short8 t1 = *(const short8*)(qrp + 32 + quad * 8);
        const int ci = row_g * HD + quad * 8;
        float c0[8], c1[8], s0[8], s1[8];
        if (cF) {
            const float* cp = (const float*)cosv + ci;
#pragma unroll
            for (int j = 0; j < 8; ++j) { c0[j] = cp[j]; c1[j] = cp[j + 32]; }
        } else {
            const ushort_t* cp = (const ushort_t*)cosv + ci;
#pragma unroll
            for (int j = 0; j < 8; ++j) { c0[j] = b2f(cp[j]); c1[j] = b2f(cp[j + 32]); }
        }
        if (sF) {
            const float* sp = (const float*)sinv + ci;
#pragma unroll
            for (int j = 0; j < 8; ++j) { s0[j] = sp[j]; s1[j] = sp[j + 32]; }
        } else {
            const ushort_t* sp = (const ushort_t*)sinv + ci;
#pragma unroll
            for (int j = 0; j < 8; ++j) { s0[j] = b2f(sp[j]); s1[j] = b2f(sp[j + 32]); }
        }
#pragma unroll
        for (int j = 0; j < 8; ++j) {
            float a = b2f((unsigned short)t0[j]), b = b2f((unsigned short)t1[j]);
            qfrag[0][j] = (short)f2b((a * c0[j] - b * s0[j]) * QS);
            qfrag[1][j] = (short)f2b((b * c1[j] + a * s1[j]) * QS);
        }
    }

    f32x4 oacc[4];
#pragma unroll
    for (int nt = 0; nt < 4; ++nt) oacc[nt] = (f32x4){0.f, 0.f, 0.f, 0.f};
    float lsum = 0.f;

    const int Lq = (qb > 0) ? qb * 64 + 128 : 64;
    const int nch = (Lq + 127) >> 7;
    const ushort_t* kbase = ktall + (size_t)kvh * KVTOT * HD;
    const ushort_t* vbase = vtall + (size_t)kvh * 96 * 2048;

    const int krow = tid >> 1;
    const int kd0 = (tid & 1) * 32;
    uint4 kreg0, kreg1, kreg2, kreg3;

#define LOADK(c_) do { \
        int p_ = (c_) * 128 + krow; \
        uint4 z_ = {0, 0, 0, 0}; \
        kreg0 = z_; kreg1 = z_; kreg2 = z_; kreg3 = z_; \
        if (p_ < Lq) { \
            int pk_ = (qb > 0) ? ((p_ < 64) ? rb64 + p_ : 960 + p_) : RLEN + p_; \
            const uint4* s_ = (const uint4*)(kbase + (size_t)pk_ * HD + kd0); \
            kreg0 = s_[0]; kreg1 = s_[1]; kreg2 = s_[2]; kreg3 = s_[3]; \
        } \
    } while (0)

    LOADK(0);   // prologue prefetch

    for (int c = 0; c < nch; ++c) {
        // ---- write K(c) to LDS (waits kreg loads issued a full chunk ago) ----
        {
            uint4* dk = (uint4*)&Ks[krow * 72 + kd0];
            dk[0] = kreg0; dk[1] = kreg1; dk[2] = kreg2; dk[3] = kreg3;
        }
        __syncthreads();

        // ---- issue K(c+1) prefetch: lands under QK^T + softmax ----
        if (c + 1 < nch) LOADK(c + 1);

        // ---- V prefetch kc0, kc1 (consumed in PV; land under QK^T) ----
        int vblk[4];
#pragma unroll
        for (int kc = 0; kc < 4; ++kc) {
            int p = c * 128 + kc * 32;
            int pk = (qb > 0) ? ((p < 64) ? rb64 + p : 960 + p) : RLEN + p;
            if (pk > KVTOT - 1) pk = KVTOT - 1;   // clamped keys have P==0 (masked)
            vblk[kc] = pk >> 5;
        }
        short8 vfA[4], vfB[4];
#pragma unroll
        for (int ntd = 0; ntd < 4; ++ntd)
            vfA[ntd] = *(const short8*)(vbase + ((size_t)vblk[0] * 64 + ntd * 16 + lq) * 32 + quad * 8);
#pragma unroll
        for (int ntd = 0; ntd < 4; ++ntd)
            vfB[ntd] = *(const short8*)(vbase + ((size_t)vblk[1] * 64 + ntd * 16 + lq) * 32 + quad * 8);

        // ---- S^T (log2 domain): mfma(K,Q), exp2, packed b64 P-store ----
        const bool lastc = (c == nch - 1) || (qb == 0);
#pragma unroll
        for (int nt = 0; nt < 8; ++nt) {
            f32x4 a = (f32x4){-FIX8, -FIX8, -FIX8, -FIX8};   // C-init folds the subtract
            a = __builtin_amdgcn_mfma_f32_16x16x32_bf16(
                *(const short8*)&Ks[(nt * 16 + lq) * 72 + quad * 8], qfrag[0], a, 0, 0, 0);
            a = __builtin_amdgcn_mfma_f32_16x16x32_bf16(
                *(const short8*)&Ks[(nt * 16 + lq) * 72 + 32 + quad * 8], qfrag[1], a, 0, 0, 0);
            float pex[4];
#pragma unroll
            for (int rr = 0; rr < 4; ++rr) {
                const int p = c * 128 + nt * 16 + quad * 4 + rr;
                float pexp = exp2f(a[rr]);
                if (lastc) {
                    bool valid;
                    if (qb > 0) valid = (p < 64) || ((p - 64) >= 1 && (p - 64) <= qrow);
                    else        valid = (p >= 1 && p <= qrow);
                    if (!valid) pexp = 0.f;
                } else if (c == 0) {
                    if (p == 64) pexp = 0.f;   // self position 0 (kv == START)
                }
                lsum += pexp;
                pex[rr] = pexp;
            }
            unsigned int w0, w1;
            asm("v_cvt_pk_bf16_f32 %0, %1, %2" : "=v"(w0) : "v"(pex[0]), "v"(pex[1]));
            asm("v_cvt_pk_bf16_f32 %0, %1, %2" : "=v"(w1) : "v"(pex[2]), "v"(pex[3]));
            *(uint2*)&pw[lq * 136 + nt * 16 + quad * 4] = make_uint2(w0, w1);
        }
        // all Ks reads done; next chunk's ds_write may proceed past this barrier
        __syncthreads();

        // ---- O += P V : kc0/kc1 from prefetch; kc2/kc3 loaded mid-loop ----
#pragma unroll
        for (int kc = 0; kc < 4; ++kc) {
            short8 pa = *(const short8*)&pw[lq * 136 + kc * 32 + quad * 8];
            short8 vf0, vf1, vf2, vf3;
            if (kc == 0)      { vf0 = vfA[0]; vf1 = vfA[1]; vf2 = vfA[2]; vf3 = vfA[3]; }
            else if (kc == 1) { vf0 = vfB[0]; vf1 = vfB[1]; vf2 = vfB[2]; vf3 = vfB[3]; }
            else {
                const int b = vblk[kc];
                vf0 = *(const short8*)(vbase + ((size_t)b * 64 + 0 * 16 + lq) * 32 + quad * 8);
                vf1 = *(const short8*)(vbase + ((size_t)b * 64 + 1 * 16 + lq) * 32 + quad * 8);
                vf2 = *(const short8*)(vbase + ((size_t)b * 64 + 2 * 16 + lq) * 32 + quad * 8);
                vf3 = *(const short8*)(vbase + ((size_t)b * 64 + 3 * 16 + lq) * 32 + quad * 8);
            }
            oacc[0] = __builtin_amdgcn_mfma_f32_16x16x32_bf16(pa, vf0, oacc[0], 0, 0, 0);
            oacc[1] = __builtin_amdgcn_mfma_f32_16x16x32_bf16(pa, vf1, oacc[1], 0, 0, 0);
            oacc[2] = __builtin_amdgcn_mfma_f32_16x16x32_bf16(pa, vf2, oacc[2], 0, 0, 0);
            oacc[3] = __builtin_amdgcn_mfma_f32_16x16x32_bf16(pa, vf3, oacc[3], 0, 0, 0);
        }
    }
#undef LOADK

    float tot = lsum;
    tot += __shfl_xor(tot, 16, 64);
    tot += __shfl_xor(tot, 32, 64);
#pragma unroll
    for (int rr = 0; rr < 4; ++rr) {
        const int qg = qb * 64 + wave * 16 + quad * 4 + rr;
        const float tr = __shfl(tot, quad * 4 + rr, 64);
        const float inv = (qg == 0) ? 0.f : 1.f / tr;
        ushort_t* orow = attno + (size_t)qg * 2048 + h * HD;
#pragma unroll
        for (int nt = 0; nt < 4; ++nt)
            orow[nt * 16 + lq] = f2b(oacc[nt][rr] * inv);
    }
}

extern "C" void kernel_launch(void* const* d_in, const int* in_sizes, int n_in,
                              void* d_out, int out_size, void* d_ws, size_t ws_size,
                              hipStream_t stream) {
    const void* hs   = d_in[0];
    const void* cosv = d_in[1];
    const void* sinv = d_in[2];
    const void* rk   = d_in[3];
    const void* rv   = d_in[4];
    const void* Wq   = d_in[5];
    const void* Wk   = d_in[6];
    const void* Wv   = d_in[7];
    const void* Wo   = d_in[8];

    char* ws = (char*)d_ws;
    ushort_t* ktall = (ushort_t*)ws;                       // 0..3MB
    ushort_t* vtall = (ushort_t*)(ws + (3u  << 20));       // 3..6MB
    ushort_t* WqkvT = (ushort_t*)(ws + (6u  << 20));       // 6..18MB [3072][2048]
    ushort_t* WoT   = (ushort_t*)(ws + (18u << 20));       // 18..26MB
    ushort_t* qkvp  = (ushort_t*)(ws + (26u << 20));       // 26..34MB (Q, swizzled blocks)
    ushort_t* attno = WqkvT;                               // alias; WqkvT dead after gemm_qkv
    ushort_t* hsb   = (ushort_t*)d_out;                    // scratch until gemm_fin

    prep_all<<<4992, 256, 0, stream>>>(rk, rv, Wq, Wk, Wv, Wo, WqkvT, WoT, ktall, vtall, hs, hsb);

    gemm_qkv<<<dim3(24, 32), 256, 0, stream>>>(hsb, WqkvT, qkvp, ktall, vtall, cosv, sinv);

    fattn<<<dim3(NH, 32), 256, 0, stream>>>(qkvp, ktall, vtall, attno, cosv, sinv);

    gemm_fin<<<dim3(16, 32), 256, 0, stream>>>(attno, WoT, d_out, 2048, 2048, hs);
}